// Round 9
// baseline (1304.616 us; speedup 1.0000x reference)
//
#include <hip/hip_runtime.h>
#include <hip/hip_bf16.h>
#include <math.h>

// GAT R9 = R8 + spin(600us) in k2 ONLY — measurement round.
// R8's k2 (~95us) is 1.7x over the stream+compute overlap model and R7
// showed the compute skeleton alone at 58.6us while "nothing-bound".
// Get k2's real counters (VGPR/occupancy/FETCH/VALU/MFMA) before touching it.

#define NN    8192
#define INF   256
#define OUTF  64
#define TILE1 16
#define BM    64
#define C0    1.0000900040501013f   // expf(9e-5) -> bf16 1.0
#define LOG2E 1.4426950408889634f

typedef __bf16 bf16x8 __attribute__((ext_vector_type(8)));
typedef float  f32x4  __attribute__((ext_vector_type(4)));
typedef int    i32x4  __attribute__((ext_vector_type(4)));

__device__ __forceinline__ void spin_ticks(long long ticks) {
    long long t0 = wall_clock64();
    while (wall_clock64() - t0 < ticks) { }
}

// k1: Wh = x@W; per-row logit factors; WhTt = bf16(Wh)^T in 32-col tiles
__global__ __launch_bounds__(256) void k1_proj(
    const float* __restrict__ x, const float* __restrict__ W,
    const float* __restrict__ alpha, __bf16* __restrict__ WhTt,
    float* __restrict__ w1, float* __restrict__ e1, float* __restrict__ f1,
    float* __restrict__ w2, float* __restrict__ e2, float* __restrict__ f2)
{
    __shared__ float xs[TILE1 * INF];
    __shared__ float shwh[TILE1 * 65];
    const int tid = threadIdx.x;
    const int i0 = blockIdx.x * TILE1;

    const float4* xsrc = (const float4*)(x + (size_t)i0 * INF);
    float4* xdst = (float4*)xs;
#pragma unroll
    for (int it = 0; it < (TILE1 * INF / 4) / 256; ++it)
        xdst[tid + it * 256] = xsrc[tid + it * 256];
    __syncthreads();

    const int wave = tid >> 6, lane = tid & 63;
    const float a1 = alpha[lane], a2 = alpha[OUTF + lane];
    const int ilbase = wave * 4;

    float acc[4] = {};
#pragma unroll 4
    for (int k4 = 0; k4 < INF / 4; ++k4) {
        float wk0 = W[(4 * k4 + 0) * OUTF + lane];
        float wk1 = W[(4 * k4 + 1) * OUTF + lane];
        float wk2 = W[(4 * k4 + 2) * OUTF + lane];
        float wk3 = W[(4 * k4 + 3) * OUTF + lane];
#pragma unroll
        for (int rr = 0; rr < 4; ++rr) {
            float4 xv = *(const float4*)&xs[(ilbase + rr) * INF + 4 * k4];
            acc[rr] = fmaf(xv.x, wk0, acc[rr]);
            acc[rr] = fmaf(xv.y, wk1, acc[rr]);
            acc[rr] = fmaf(xv.z, wk2, acc[rr]);
            acc[rr] = fmaf(xv.w, wk3, acc[rr]);
        }
    }

#pragma unroll
    for (int rr = 0; rr < 4; ++rr) {
        const int il = ilbase + rr;
        const int i  = i0 + il;
        float a = acc[rr];
        float v1 = a * a1, v2 = a * a2;
#pragma unroll
        for (int off = 32; off > 0; off >>= 1) {
            v1 += __shfl_xor(v1, off);
            v2 += __shfl_xor(v2, off);
        }
        if (lane == 0) {
            float v1L = v1 * LOG2E, v2L = v2 * LOG2E;
            w1[i] = v1L; e1[i] = exp2f(v1L); f1[i] = exp2f(0.2f * v1L);
            w2[i] = v2L; e2[i] = exp2f(v2L); f2[i] = exp2f(0.2f * v2L);
        }
        shwh[il * 65 + lane] = a;
    }
    __syncthreads();

#pragma unroll
    for (int it = 0; it < (OUTF * TILE1) / 256; ++it) {
        int idx = it * 256 + tid;
        int f = idx / TILE1, il = idx % TILE1;
        int j = i0 + il;
        WhTt[((size_t)(j >> 5) * 64 + f) * 32 + (j & 31)] = (__bf16)shwh[il * 65 + f];
    }
}

// k2: stream adj directly into A-frags; P via factorized exp; 4+1 MFMAs.
// +spin 60000 ticks (measurement: counters visible in top-5; real = dur-600us)
template <int SPL>
__global__ __launch_bounds__(256) void k2_attn(
    const int* __restrict__ adj,
    const float* __restrict__ w1g, const float* __restrict__ e1g,
    const float* __restrict__ f1g, const float* __restrict__ w2g,
    const float* __restrict__ e2g, const float* __restrict__ f2g,
    const __bf16* __restrict__ WhTt, float* __restrict__ pacc,
    float* __restrict__ pz)
{
    constexpr int CPS = NN / SPL;
    __shared__ float nw2s[CPS], e2s[CPS], f2s[CPS];
    __shared__ float w1s[BM], e1s[BM], f1s[BM];
    const int tid = threadIdx.x;
    const int s = blockIdx.x % SPL;
    const int row_tile = blockIdx.x / SPL;
    const int jb = s * CPS;

    for (int i = tid; i < CPS; i += 256) {
        nw2s[i] = -w2g[jb + i];
        e2s[i]  =  e2g[jb + i];
        f2s[i]  =  f2g[jb + i];
    }
    if (tid < BM) {
        int r = row_tile * BM + tid;
        w1s[tid] = w1g[r]; e1s[tid] = e1g[r]; f1s[tid] = f1g[r];
    }
    __syncthreads();

    const int wave = tid >> 6, lane = tid & 63;
    const int fl = lane & 15, g = lane >> 4;
    const int rw0 = row_tile * BM + wave * 16;
    const int row = rw0 + fl;
    const float w1r = w1s[wave * 16 + fl];
    const float e1r = e1s[wave * 16 + fl];
    const float f1r = f1s[wave * 16 + fl];

    f32x4 acc0 = {}, acc1 = {}, acc2 = {}, acc3 = {}, accZ = {};
    bf16x8 ones;
#pragma unroll
    for (int e = 0; e < 8; ++e) ones[e] = (__bf16)1.0f;

    const i32x4* ap = (const i32x4*)(adj + (size_t)row * NN + jb + 8 * g);
    const __bf16* bb = WhTt + (size_t)(jb >> 5) * (64 * 32) + fl * 32 + g * 8;

#pragma unroll 2
    for (int t = 0; t < CPS / 32; ++t) {
        i32x4 a0 = __builtin_nontemporal_load(ap + 8 * t);
        i32x4 a1 = __builtin_nontemporal_load(ap + 8 * t + 1);
        const int co = 32 * t + 8 * g;
        float4 n0 = *(const float4*)(nw2s + co), n1 = *(const float4*)(nw2s + co + 4);
        float4 ee0 = *(const float4*)(e2s + co), ee1 = *(const float4*)(e2s + co + 4);
        float4 ff0 = *(const float4*)(f2s + co), ff1 = *(const float4*)(f2s + co + 4);

        int   ai[8] = {a0.x, a0.y, a0.z, a0.w, a1.x, a1.y, a1.z, a1.w};
        float nn[8] = {n0.x, n0.y, n0.z, n0.w, n1.x, n1.y, n1.z, n1.w};
        float ev[8] = {ee0.x, ee0.y, ee0.z, ee0.w, ee1.x, ee1.y, ee1.z, ee1.w};
        float fv[8] = {ff0.x, ff0.y, ff0.z, ff0.w, ff1.x, ff1.y, ff1.z, ff1.w};

        bf16x8 pa;
#pragma unroll
        for (int e = 0; e < 8; ++e) {
            bool pos = (w1r >= nn[e]);            // w1_i + w2_j >= 0
            float p = (pos ? e1r : f1r) * (pos ? ev[e] : fv[e]);
            p = (ai[e] > 0) ? p : C0;             // mask fill
            pa[e] = (__bf16)p;
        }

        const __bf16* bt = bb + (size_t)t * 2048;
        acc0 = __builtin_amdgcn_mfma_f32_16x16x32_bf16(pa, *(const bf16x8*)(bt +    0), acc0, 0, 0, 0);
        acc1 = __builtin_amdgcn_mfma_f32_16x16x32_bf16(pa, *(const bf16x8*)(bt +  512), acc1, 0, 0, 0);
        acc2 = __builtin_amdgcn_mfma_f32_16x16x32_bf16(pa, *(const bf16x8*)(bt + 1024), acc2, 0, 0, 0);
        acc3 = __builtin_amdgcn_mfma_f32_16x16x32_bf16(pa, *(const bf16x8*)(bt + 1536), acc3, 0, 0, 0);
        accZ = __builtin_amdgcn_mfma_f32_16x16x32_bf16(pa, ones, accZ, 0, 0, 0);
    }

    if (fl == 0) {
#pragma unroll
        for (int i = 0; i < 4; ++i)
            pz[(size_t)s * NN + rw0 + 4 * g + i] = accZ[i];
    }
    float* prow = pacc + ((size_t)s * NN + rw0 + 4 * g) * OUTF + fl;
#pragma unroll
    for (int i = 0; i < 4; ++i) {
        __builtin_nontemporal_store(acc0[i], prow + (size_t)i * OUTF + 0);
        __builtin_nontemporal_store(acc1[i], prow + (size_t)i * OUTF + 16);
        __builtin_nontemporal_store(acc2[i], prow + (size_t)i * OUTF + 32);
        __builtin_nontemporal_store(acc3[i], prow + (size_t)i * OUTF + 48);
    }
    spin_ticks(60000);
}

// k3: combine splits, divide by Z, add bias
template <int SPL>
__global__ __launch_bounds__(256) void k3_final(
    const float* __restrict__ pacc, const float* __restrict__ pz,
    const float* __restrict__ bias, float* __restrict__ out)
{
    const int t = blockIdx.x * 256 + threadIdx.x;
    const int i = t >> 6, f = t & 63;
    float num = 0.f, z = 0.f;
#pragma unroll
    for (int s = 0; s < SPL; ++s) {
        num += pacc[(size_t)s * NN * OUTF + t];
        z   += pz[(size_t)s * NN + i];
    }
    out[t] = num / z + bias[f];
}

extern "C" void kernel_launch(void* const* d_in, const int* in_sizes, int n_in,
                              void* d_out, int out_size, void* d_ws, size_t ws_size,
                              hipStream_t stream)
{
    const float* x     = (const float*)d_in[0];
    const int*   adj   = (const int*)d_in[1];
    const float* W     = (const float*)d_in[2];
    const float* alpha = (const float*)d_in[3];
    const float* bias  = (const float*)d_in[4];
    float* out = (float*)d_out;

    char* ws = (char*)d_ws;
    size_t off = 0;
    __bf16* WhTt = (__bf16*)(ws + off); off += (size_t)NN * OUTF * 2;
    float* w1 = (float*)(ws + off); off += (size_t)NN * 4;
    float* e1 = (float*)(ws + off); off += (size_t)NN * 4;
    float* f1 = (float*)(ws + off); off += (size_t)NN * 4;
    float* w2 = (float*)(ws + off); off += (size_t)NN * 4;
    float* e2 = (float*)(ws + off); off += (size_t)NN * 4;
    float* f2 = (float*)(ws + off); off += (size_t)NN * 4;

    const size_t need16 = off + (size_t)16 * NN * 4 + (size_t)16 * NN * OUTF * 4;
    const int split = (ws_size >= need16) ? 16 : 8;
    float* pz   = (float*)(ws + off); off += (size_t)split * NN * 4;
    float* pacc = (float*)(ws + off); off += (size_t)split * NN * OUTF * 4;

    k1_proj<<<NN / TILE1, 256, 0, stream>>>(x, W, alpha, WhTt, w1, e1, f1, w2, e2, f2);
    if (split == 16) {
        k2_attn<16><<<(NN / BM) * 16, 256, 0, stream>>>(adj, w1, e1, f1, w2, e2, f2, WhTt, pacc, pz);
        k3_final<16><<<(NN * OUTF) / 256, 256, 0, stream>>>(pacc, pz, bias, out);
    } else {
        k2_attn<8><<<(NN / BM) * 8, 256, 0, stream>>>(adj, w1, e1, f1, w2, e2, f2, WhTt, pacc, pz);
        k3_final<8><<<(NN * OUTF) / 256, 256, 0, stream>>>(pacc, pz, bias, out);
    }
}

// Round 10
// 105.233 us; speedup vs baseline: 12.3974x; 12.3974x over previous
//
#include <hip/hip_runtime.h>
#include <hip/hip_bf16.h>
#include <math.h>

// GAT: out = softmax(mask(lrelu(w1 + w2^T), adj)) @ (x@W) + bias
// R10: max-trick P = max(e1*e2, f1*f2) (no compare path, no nw2s/w1s),
// explicit adj prefetch, __launch_bounds__(256,6), plain (non-nt) adj loads.
// k2 lane (fl,g) builds its own A-frag from adj row fl, cols 8g..8g+7.

#define NN    8192
#define INF   256
#define OUTF  64
#define TILE1 16
#define BM    64
#define SPL   16
#define CPS   (NN / SPL)    // 512
#define NT    (CPS / 32)    // 16
#define C0    1.0000900040501013f   // expf(9e-5)
#define LOG2E 1.4426950408889634f

typedef __bf16 bf16x8 __attribute__((ext_vector_type(8)));
typedef float  f32x4  __attribute__((ext_vector_type(4)));
typedef int    i32x4  __attribute__((ext_vector_type(4)));

// k1: Wh = x@W; row/col softmax factors e=exp(w), f=exp(0.2w); WhTt tiled bf16
__global__ __launch_bounds__(256) void k1_proj(
    const float* __restrict__ x, const float* __restrict__ W,
    const float* __restrict__ alpha, __bf16* __restrict__ WhTt,
    float* __restrict__ e1, float* __restrict__ f1,
    float* __restrict__ e2, float* __restrict__ f2)
{
    __shared__ float xs[TILE1 * INF];
    __shared__ float shwh[TILE1 * 65];
    const int tid = threadIdx.x;
    const int i0 = blockIdx.x * TILE1;

    const float4* xsrc = (const float4*)(x + (size_t)i0 * INF);
    float4* xdst = (float4*)xs;
#pragma unroll
    for (int it = 0; it < (TILE1 * INF / 4) / 256; ++it)
        xdst[tid + it * 256] = xsrc[tid + it * 256];
    __syncthreads();

    const int wave = tid >> 6, lane = tid & 63;
    const float a1 = alpha[lane], a2 = alpha[OUTF + lane];
    const int ilbase = wave * 4;

    float acc[4] = {};
#pragma unroll 4
    for (int k4 = 0; k4 < INF / 4; ++k4) {
        float wk0 = W[(4 * k4 + 0) * OUTF + lane];
        float wk1 = W[(4 * k4 + 1) * OUTF + lane];
        float wk2 = W[(4 * k4 + 2) * OUTF + lane];
        float wk3 = W[(4 * k4 + 3) * OUTF + lane];
#pragma unroll
        for (int rr = 0; rr < 4; ++rr) {
            float4 xv = *(const float4*)&xs[(ilbase + rr) * INF + 4 * k4];
            acc[rr] = fmaf(xv.x, wk0, acc[rr]);
            acc[rr] = fmaf(xv.y, wk1, acc[rr]);
            acc[rr] = fmaf(xv.z, wk2, acc[rr]);
            acc[rr] = fmaf(xv.w, wk3, acc[rr]);
        }
    }

#pragma unroll
    for (int rr = 0; rr < 4; ++rr) {
        const int il = ilbase + rr;
        const int i  = i0 + il;
        float a = acc[rr];
        float v1 = a * a1, v2 = a * a2;
#pragma unroll
        for (int off = 32; off > 0; off >>= 1) {
            v1 += __shfl_xor(v1, off);
            v2 += __shfl_xor(v2, off);
        }
        if (lane == 0) {
            float v1L = v1 * LOG2E, v2L = v2 * LOG2E;
            e1[i] = exp2f(v1L); f1[i] = exp2f(0.2f * v1L);
            e2[i] = exp2f(v2L); f2[i] = exp2f(0.2f * v2L);
        }
        shwh[il * 65 + lane] = a;
    }
    __syncthreads();

#pragma unroll
    for (int it = 0; it < (OUTF * TILE1) / 256; ++it) {
        int idx = it * 256 + tid;
        int f = idx / TILE1, il = idx % TILE1;
        int j = i0 + il;
        WhTt[((size_t)(j >> 5) * 64 + f) * 32 + (j & 31)] = (__bf16)shwh[il * 65 + f];
    }
}

// k2: stream adj into A-frags; P = mask ? max(e1*e2, f1*f2) : C0; 4+1 MFMAs.
__global__ __launch_bounds__(256, 6) void k2_attn(
    const int* __restrict__ adj,
    const float* __restrict__ e1g, const float* __restrict__ f1g,
    const float* __restrict__ e2g, const float* __restrict__ f2g,
    const __bf16* __restrict__ WhTt, float* __restrict__ pacc,
    float* __restrict__ pz)
{
    __shared__ float e2s[CPS], f2s[CPS];
    const int tid = threadIdx.x;
    const int s  = blockIdx.x % SPL;   // bid%8 == s%8 -> slice pinned to one XCD L2
    const int rt = blockIdx.x / SPL;
    const int jb = s * CPS;

#pragma unroll
    for (int i = 0; i < CPS / 256; ++i) {
        e2s[tid + 256 * i] = e2g[jb + tid + 256 * i];
        f2s[tid + 256 * i] = f2g[jb + tid + 256 * i];
    }
    __syncthreads();

    const int wave = tid >> 6, lane = tid & 63;
    const int fl = lane & 15, g = lane >> 4;
    const int rw0 = rt * BM + wave * 16;
    const int row = rw0 + fl;
    const float e1r = e1g[row], f1r = f1g[row];

    f32x4 acc0 = {}, acc1 = {}, acc2 = {}, acc3 = {}, accZ = {};
    bf16x8 ones;
#pragma unroll
    for (int e = 0; e < 8; ++e) ones[e] = (__bf16)1.0f;

    const i32x4*  ap = (const i32x4*)(adj + (size_t)row * NN + jb) + 2 * g;
    const __bf16* bb = WhTt + (size_t)(jb >> 5) * 2048 + fl * 32 + g * 8;
    const float*  eb = e2s + 8 * g;
    const float*  fb = f2s + 8 * g;

    // software pipeline: adj for iter t+1 in flight during iter t's compute
    i32x4 a0 = ap[0], a1 = ap[1];

#pragma unroll
    for (int t = 0; t < NT; ++t) {
        const i32x4 ca0 = a0, ca1 = a1;
        if (t + 1 < NT) { a0 = ap[8 * (t + 1)]; a1 = ap[8 * (t + 1) + 1]; }

        const int co = 32 * t;
        float4 ee0 = *(const float4*)(eb + co), ee1 = *(const float4*)(eb + co + 4);
        float4 ff0 = *(const float4*)(fb + co), ff1 = *(const float4*)(fb + co + 4);

        int   ai[8] = {ca0.x, ca0.y, ca0.z, ca0.w, ca1.x, ca1.y, ca1.z, ca1.w};
        float ev[8] = {ee0.x, ee0.y, ee0.z, ee0.w, ee1.x, ee1.y, ee1.z, ee1.w};
        float fv[8] = {ff0.x, ff0.y, ff0.z, ff0.w, ff1.x, ff1.y, ff1.z, ff1.w};

        bf16x8 pa;
#pragma unroll
        for (int e = 0; e < 8; ++e) {
            float pe = fmaxf(e1r * ev[e], f1r * fv[e]);  // exp(lrelu(w1+w2))
            pa[e] = (__bf16)((ai[e] > 0) ? pe : C0);
        }

        const __bf16* bt = bb + (size_t)t * 2048;
        acc0 = __builtin_amdgcn_mfma_f32_16x16x32_bf16(pa, *(const bf16x8*)(bt +    0), acc0, 0, 0, 0);
        acc1 = __builtin_amdgcn_mfma_f32_16x16x32_bf16(pa, *(const bf16x8*)(bt +  512), acc1, 0, 0, 0);
        acc2 = __builtin_amdgcn_mfma_f32_16x16x32_bf16(pa, *(const bf16x8*)(bt + 1024), acc2, 0, 0, 0);
        acc3 = __builtin_amdgcn_mfma_f32_16x16x32_bf16(pa, *(const bf16x8*)(bt + 1536), acc3, 0, 0, 0);
        accZ = __builtin_amdgcn_mfma_f32_16x16x32_bf16(pa, ones, accZ, 0, 0, 0);
    }

    if (fl == 0) {
#pragma unroll
        for (int i = 0; i < 4; ++i)
            pz[(size_t)s * NN + rw0 + 4 * g + i] = accZ[i];
    }
    float* prow = pacc + ((size_t)s * NN + rw0 + 4 * g) * OUTF + fl;
#pragma unroll
    for (int i = 0; i < 4; ++i) {
        __builtin_nontemporal_store(acc0[i], prow + (size_t)i * OUTF + 0);
        __builtin_nontemporal_store(acc1[i], prow + (size_t)i * OUTF + 16);
        __builtin_nontemporal_store(acc2[i], prow + (size_t)i * OUTF + 32);
        __builtin_nontemporal_store(acc3[i], prow + (size_t)i * OUTF + 48);
    }
}

// k3: combine splits, divide by Z, add bias
__global__ __launch_bounds__(256) void k3_final(
    const float* __restrict__ pacc, const float* __restrict__ pz,
    const float* __restrict__ bias, float* __restrict__ out)
{
    const int t = blockIdx.x * 256 + threadIdx.x;
    const int i = t >> 6, f = t & 63;
    float num = 0.f, z = 0.f;
#pragma unroll
    for (int s = 0; s < SPL; ++s) {
        num += pacc[(size_t)s * NN * OUTF + t];
        z   += pz[(size_t)s * NN + i];
    }
    out[t] = num / z + bias[f];
}

extern "C" void kernel_launch(void* const* d_in, const int* in_sizes, int n_in,
                              void* d_out, int out_size, void* d_ws, size_t ws_size,
                              hipStream_t stream)
{
    const float* x     = (const float*)d_in[0];
    const int*   adj   = (const int*)d_in[1];
    const float* W     = (const float*)d_in[2];
    const float* alpha = (const float*)d_in[3];
    const float* bias  = (const float*)d_in[4];
    float* out = (float*)d_out;

    char* ws = (char*)d_ws;
    size_t off = 0;
    __bf16* WhTt = (__bf16*)(ws + off); off += (size_t)NN * OUTF * 2;
    float* e1 = (float*)(ws + off); off += (size_t)NN * 4;
    float* f1 = (float*)(ws + off); off += (size_t)NN * 4;
    float* e2 = (float*)(ws + off); off += (size_t)NN * 4;
    float* f2 = (float*)(ws + off); off += (size_t)NN * 4;
    float* pz   = (float*)(ws + off); off += (size_t)SPL * NN * 4;
    float* pacc = (float*)(ws + off); off += (size_t)SPL * NN * OUTF * 4;

    k1_proj<<<NN / TILE1, 256, 0, stream>>>(x, W, alpha, WhTt, e1, f1, e2, f2);
    k2_attn<<<(NN / BM) * SPL, 256, 0, stream>>>(adj, e1, f1, e2, f2, WhTt, pacc, pz);
    k3_final<<<(NN * OUTF) / 256, 256, 0, stream>>>(pacc, pz, bias, out);
}

// Round 11
// 84.312 us; speedup vs baseline: 15.4737x; 1.2481x over previous
//
#include <hip/hip_runtime.h>
#include <hip/hip_bf16.h>
#include <math.h>

// GAT: out = softmax(mask(lrelu(w1 + w2^T), adj)) @ (x@W) + bias
// R11: BM=128, each wave owns TWO 16-row A-tiles (r, r+64) sharing the 4
// B-fragment loads per k-step (halves latency-exposed vmem per unit work,
// doubles per-wave independent chains). P = mask ? max(e1*e2, f1*f2) : C0.
// setprio(1) around MFMA cluster (independent waves, attn-like regime).

#define NN    8192
#define INF   256
#define OUTF  64
#define TILE1 16
#define BM    128
#define SPL   16
#define CPS   (NN / SPL)    // 512
#define NT    (CPS / 32)    // 16
#define C0    1.0000900040501013f   // expf(9e-5)
#define LOG2E 1.4426950408889634f

typedef __bf16 bf16x8 __attribute__((ext_vector_type(8)));
typedef float  f32x4  __attribute__((ext_vector_type(4)));
typedef int    i32x4  __attribute__((ext_vector_type(4)));

// k1: Wh = x@W; row/col softmax factors e=exp(w), f=exp(0.2w); WhTt tiled bf16
__global__ __launch_bounds__(256) void k1_proj(
    const float* __restrict__ x, const float* __restrict__ W,
    const float* __restrict__ alpha, __bf16* __restrict__ WhTt,
    float* __restrict__ e1, float* __restrict__ f1,
    float* __restrict__ e2, float* __restrict__ f2)
{
    __shared__ float xs[TILE1 * INF];
    __shared__ float shwh[TILE1 * 65];
    const int tid = threadIdx.x;
    const int i0 = blockIdx.x * TILE1;

    const float4* xsrc = (const float4*)(x + (size_t)i0 * INF);
    float4* xdst = (float4*)xs;
#pragma unroll
    for (int it = 0; it < (TILE1 * INF / 4) / 256; ++it)
        xdst[tid + it * 256] = xsrc[tid + it * 256];
    __syncthreads();

    const int wave = tid >> 6, lane = tid & 63;
    const float a1 = alpha[lane], a2 = alpha[OUTF + lane];
    const int ilbase = wave * 4;

    float acc[4] = {};
#pragma unroll 4
    for (int k4 = 0; k4 < INF / 4; ++k4) {
        float wk0 = W[(4 * k4 + 0) * OUTF + lane];
        float wk1 = W[(4 * k4 + 1) * OUTF + lane];
        float wk2 = W[(4 * k4 + 2) * OUTF + lane];
        float wk3 = W[(4 * k4 + 3) * OUTF + lane];
#pragma unroll
        for (int rr = 0; rr < 4; ++rr) {
            float4 xv = *(const float4*)&xs[(ilbase + rr) * INF + 4 * k4];
            acc[rr] = fmaf(xv.x, wk0, acc[rr]);
            acc[rr] = fmaf(xv.y, wk1, acc[rr]);
            acc[rr] = fmaf(xv.z, wk2, acc[rr]);
            acc[rr] = fmaf(xv.w, wk3, acc[rr]);
        }
    }

#pragma unroll
    for (int rr = 0; rr < 4; ++rr) {
        const int il = ilbase + rr;
        const int i  = i0 + il;
        float a = acc[rr];
        float v1 = a * a1, v2 = a * a2;
#pragma unroll
        for (int off = 32; off > 0; off >>= 1) {
            v1 += __shfl_xor(v1, off);
            v2 += __shfl_xor(v2, off);
        }
        if (lane == 0) {
            float v1L = v1 * LOG2E, v2L = v2 * LOG2E;
            e1[i] = exp2f(v1L); f1[i] = exp2f(0.2f * v1L);
            e2[i] = exp2f(v2L); f2[i] = exp2f(0.2f * v2L);
        }
        shwh[il * 65 + lane] = a;
    }
    __syncthreads();

#pragma unroll
    for (int it = 0; it < (OUTF * TILE1) / 256; ++it) {
        int idx = it * 256 + tid;
        int f = idx / TILE1, il = idx % TILE1;
        int j = i0 + il;
        WhTt[((size_t)(j >> 5) * 64 + f) * 32 + (j & 31)] = (__bf16)shwh[il * 65 + f];
    }
}

// k2: two A-tiles per wave share B-frags; 8+2 MFMAs per k-step.
__global__ __launch_bounds__(256, 4) void k2_attn(
    const int* __restrict__ adj,
    const float* __restrict__ e1g, const float* __restrict__ f1g,
    const float* __restrict__ e2g, const float* __restrict__ f2g,
    const __bf16* __restrict__ WhTt, float* __restrict__ pacc,
    float* __restrict__ pz)
{
    __shared__ float e2s[CPS], f2s[CPS];
    const int tid = threadIdx.x;
    const int s  = blockIdx.x % SPL;
    const int rt = blockIdx.x / SPL;
    const int jb = s * CPS;

#pragma unroll
    for (int i = 0; i < CPS / 256; ++i) {
        e2s[tid + 256 * i] = e2g[jb + tid + 256 * i];
        f2s[tid + 256 * i] = f2g[jb + tid + 256 * i];
    }
    __syncthreads();

    const int wave = tid >> 6, lane = tid & 63;
    const int fl = lane & 15, g = lane >> 4;
    const int rw0 = rt * BM + wave * 16;       // tile A rows rw0..rw0+15
    const int rowA = rw0 + fl;                 // tile B rows rw0+64..+79
    const float e1A = e1g[rowA], f1A = f1g[rowA];
    const float e1B = e1g[rowA + 64], f1B = f1g[rowA + 64];

    f32x4 aA0 = {}, aA1 = {}, aA2 = {}, aA3 = {}, aAZ = {};
    f32x4 aB0 = {}, aB1 = {}, aB2 = {}, aB3 = {}, aBZ = {};
    bf16x8 ones;
#pragma unroll
    for (int e = 0; e < 8; ++e) ones[e] = (__bf16)1.0f;

    const i32x4*  apA = (const i32x4*)(adj + (size_t)rowA * NN + jb) + 2 * g;
    const i32x4*  apB = apA + (size_t)64 * NN / 4;
    const __bf16* bb  = WhTt + (size_t)(jb >> 5) * 2048 + fl * 32 + g * 8;
    const float*  eb = e2s + 8 * g;
    const float*  fb = f2s + 8 * g;

    // 1-deep prefetch of all 4 adj loads
    i32x4 A0 = apA[0], A1 = apA[1], B0 = apB[0], B1 = apB[1];

#pragma unroll
    for (int t = 0; t < NT; ++t) {
        const i32x4 cA0 = A0, cA1 = A1, cB0 = B0, cB1 = B1;
        if (t + 1 < NT) {
            A0 = apA[8 * (t + 1)]; A1 = apA[8 * (t + 1) + 1];
            B0 = apB[8 * (t + 1)]; B1 = apB[8 * (t + 1) + 1];
        }

        const int co = 32 * t;
        float4 ee0 = *(const float4*)(eb + co), ee1 = *(const float4*)(eb + co + 4);
        float4 ff0 = *(const float4*)(fb + co), ff1 = *(const float4*)(fb + co + 4);

        int   aiA[8] = {cA0.x, cA0.y, cA0.z, cA0.w, cA1.x, cA1.y, cA1.z, cA1.w};
        int   aiB[8] = {cB0.x, cB0.y, cB0.z, cB0.w, cB1.x, cB1.y, cB1.z, cB1.w};
        float ev[8]  = {ee0.x, ee0.y, ee0.z, ee0.w, ee1.x, ee1.y, ee1.z, ee1.w};
        float fv[8]  = {ff0.x, ff0.y, ff0.z, ff0.w, ff1.x, ff1.y, ff1.z, ff1.w};

        bf16x8 paA, paB;
#pragma unroll
        for (int e = 0; e < 8; ++e) {
            float peA = fmaxf(e1A * ev[e], f1A * fv[e]);
            float peB = fmaxf(e1B * ev[e], f1B * fv[e]);
            paA[e] = (__bf16)((aiA[e] > 0) ? peA : C0);
            paB[e] = (__bf16)((aiB[e] > 0) ? peB : C0);
        }

        const __bf16* bt = bb + (size_t)t * 2048;
        bf16x8 b0 = *(const bf16x8*)(bt +    0);
        bf16x8 b1 = *(const bf16x8*)(bt +  512);
        bf16x8 b2 = *(const bf16x8*)(bt + 1024);
        bf16x8 b3 = *(const bf16x8*)(bt + 1536);

        __builtin_amdgcn_s_setprio(1);
        aA0 = __builtin_amdgcn_mfma_f32_16x16x32_bf16(paA, b0, aA0, 0, 0, 0);
        aB0 = __builtin_amdgcn_mfma_f32_16x16x32_bf16(paB, b0, aB0, 0, 0, 0);
        aA1 = __builtin_amdgcn_mfma_f32_16x16x32_bf16(paA, b1, aA1, 0, 0, 0);
        aB1 = __builtin_amdgcn_mfma_f32_16x16x32_bf16(paB, b1, aB1, 0, 0, 0);
        aA2 = __builtin_amdgcn_mfma_f32_16x16x32_bf16(paA, b2, aA2, 0, 0, 0);
        aB2 = __builtin_amdgcn_mfma_f32_16x16x32_bf16(paB, b2, aB2, 0, 0, 0);
        aA3 = __builtin_amdgcn_mfma_f32_16x16x32_bf16(paA, b3, aA3, 0, 0, 0);
        aB3 = __builtin_amdgcn_mfma_f32_16x16x32_bf16(paB, b3, aB3, 0, 0, 0);
        aAZ = __builtin_amdgcn_mfma_f32_16x16x32_bf16(paA, ones, aAZ, 0, 0, 0);
        aBZ = __builtin_amdgcn_mfma_f32_16x16x32_bf16(paB, ones, aBZ, 0, 0, 0);
        __builtin_amdgcn_s_setprio(0);
    }

    if (fl == 0) {
#pragma unroll
        for (int i = 0; i < 4; ++i) {
            pz[(size_t)s * NN + rw0 + 4 * g + i]      = aAZ[i];
            pz[(size_t)s * NN + rw0 + 64 + 4 * g + i] = aBZ[i];
        }
    }
    float* prA = pacc + ((size_t)s * NN + rw0 + 4 * g) * OUTF + fl;
    float* prB = prA + (size_t)64 * OUTF;
#pragma unroll
    for (int i = 0; i < 4; ++i) {
        __builtin_nontemporal_store(aA0[i], prA + (size_t)i * OUTF + 0);
        __builtin_nontemporal_store(aA1[i], prA + (size_t)i * OUTF + 16);
        __builtin_nontemporal_store(aA2[i], prA + (size_t)i * OUTF + 32);
        __builtin_nontemporal_store(aA3[i], prA + (size_t)i * OUTF + 48);
        __builtin_nontemporal_store(aB0[i], prB + (size_t)i * OUTF + 0);
        __builtin_nontemporal_store(aB1[i], prB + (size_t)i * OUTF + 16);
        __builtin_nontemporal_store(aB2[i], prB + (size_t)i * OUTF + 32);
        __builtin_nontemporal_store(aB3[i], prB + (size_t)i * OUTF + 48);
    }
}

// k3: combine splits, divide by Z, add bias
__global__ __launch_bounds__(256) void k3_final(
    const float* __restrict__ pacc, const float* __restrict__ pz,
    const float* __restrict__ bias, float* __restrict__ out)
{
    const int t = blockIdx.x * 256 + threadIdx.x;
    const int i = t >> 6, f = t & 63;
    float num = 0.f, z = 0.f;
#pragma unroll
    for (int s = 0; s < SPL; ++s) {
        num += pacc[(size_t)s * NN * OUTF + t];
        z   += pz[(size_t)s * NN + i];
    }
    out[t] = num / z + bias[f];
}

extern "C" void kernel_launch(void* const* d_in, const int* in_sizes, int n_in,
                              void* d_out, int out_size, void* d_ws, size_t ws_size,
                              hipStream_t stream)
{
    const float* x     = (const float*)d_in[0];
    const int*   adj   = (const int*)d_in[1];
    const float* W     = (const float*)d_in[2];
    const float* alpha = (const float*)d_in[3];
    const float* bias  = (const float*)d_in[4];
    float* out = (float*)d_out;

    char* ws = (char*)d_ws;
    size_t off = 0;
    __bf16* WhTt = (__bf16*)(ws + off); off += (size_t)NN * OUTF * 2;
    float* e1 = (float*)(ws + off); off += (size_t)NN * 4;
    float* f1 = (float*)(ws + off); off += (size_t)NN * 4;
    float* e2 = (float*)(ws + off); off += (size_t)NN * 4;
    float* f2 = (float*)(ws + off); off += (size_t)NN * 4;
    float* pz   = (float*)(ws + off); off += (size_t)SPL * NN * 4;
    float* pacc = (float*)(ws + off); off += (size_t)SPL * NN * OUTF * 4;

    k1_proj<<<NN / TILE1, 256, 0, stream>>>(x, W, alpha, WhTt, e1, f1, e2, f2);
    k2_attn<<<(NN / BM) * SPL, 256, 0, stream>>>(adj, e1, f1, e2, f2, WhTt, pacc, pz);
    k3_final<<<(NN * OUTF) / 256, 256, 0, stream>>>(pacc, pz, bias, out);
}